// Round 6
// baseline (768.096 us; speedup 1.0000x reference)
//
#include <hip/hip_runtime.h>
#include <hip/hip_bf16.h>
#include <stdint.h>

// Problem constants
#define A_N 8
#define B_N 32768
#define IN_N 128
#define OUT_N 32
#define SAF 160      // IN + OUT
#define H_N 128
#define D_N 32
#define KD_N 128     // K*D
#define CIN_N 256    // critic input = H + K*D
#define CHUNKS 128   // stats chunks over B
#define EPSV 1e-5f
#define ENC_KP 192   // enc K padded 160 -> 192

typedef unsigned int u32;
typedef unsigned short u16;
typedef __attribute__((ext_vector_type(8))) short short8;    // 8 bf16 (4 VGPRs)
typedef __attribute__((ext_vector_type(4))) float floatx4;   // MFMA C/D

__device__ __forceinline__ float bf_lo(u32 u){ return __uint_as_float(u << 16); }
__device__ __forceinline__ float bf_hi(u32 u){ return __uint_as_float(u & 0xffff0000u); }
__device__ __forceinline__ float bf2f(u16 b){ return __uint_as_float(((u32)b) << 16); }
__device__ __forceinline__ u16 f2bf(float f){
  u32 u = __float_as_uint(f);
  return (u16)((u + 0x7fffu + ((u >> 16) & 1u)) >> 16);
}
__device__ __forceinline__ float lrelu(float x){ return x > 0.f ? x : 0.01f * x; }

// ---------------------------------------------------------------------------
// Stage 1: BN statistics (sum, sumsq) per (agent, feature).
// ---------------------------------------------------------------------------
__global__ __launch_bounds__(256) void k_stats(
    const float* __restrict__ states, const float* __restrict__ actions,
    float* __restrict__ part)
{
  int a = blockIdx.y;
  int chunk = blockIdx.x;
  int t = threadIdx.x;
  int r0 = chunk * (B_N / CHUNKS);   // 256 rows per chunk
  __shared__ float red[512];
  {
    int f = t & 127, half = t >> 7;
    const float* p = states + ((size_t)a * B_N + r0 + half) * IN_N + f;
    float s1 = 0.f, s2 = 0.f;
    for (int it = 0; it < 128; ++it){
      float v = p[(size_t)(2 * it) * IN_N];
      s1 += v; s2 += v * v;
    }
    red[t] = s1; red[256 + t] = s2;
    __syncthreads();
    if (t < 128){
      float a1 = red[t] + red[t + 128];
      float a2 = red[256 + t] + red[256 + t + 128];
      size_t o = (((size_t)a * CHUNKS + chunk) * SAF + t) * 2;
      part[o] = a1; part[o + 1] = a2;
    }
    __syncthreads();
  }
  {
    int f = t & 31, g = t >> 5;
    const float* p = actions + ((size_t)a * B_N + r0 + g) * OUT_N + f;
    float s1 = 0.f, s2 = 0.f;
    for (int it = 0; it < 32; ++it){
      float v = p[(size_t)(8 * it) * OUT_N];
      s1 += v; s2 += v * v;
    }
    red[t] = s1; red[256 + t] = s2;
    __syncthreads();
    if (t < 32){
      float a1 = 0.f, a2 = 0.f;
      #pragma unroll
      for (int gg = 0; gg < 8; ++gg){
        a1 += red[t + 32 * gg];
        a2 += red[256 + t + 32 * gg];
      }
      size_t o = (((size_t)a * CHUNKS + chunk) * SAF + 128 + t) * 2;
      part[o] = a1; part[o + 1] = a2;
    }
  }
}

__global__ void k_finalize(const float* __restrict__ part,
                           float* __restrict__ meanArr, float* __restrict__ istdArr)
{
  int idx = blockIdx.x * blockDim.x + threadIdx.x;
  if (idx >= A_N * SAF) return;
  int a = idx / SAF, f = idx % SAF;
  float s1 = 0.f, s2 = 0.f;
  for (int c = 0; c < CHUNKS; ++c){
    size_t o = (((size_t)a * CHUNKS + c) * SAF + f) * 2;
    s1 += part[o]; s2 += part[o + 1];
  }
  float m = s1 * (1.f / B_N);
  float v = s2 * (1.f / B_N) - m * m;
  if (v < 0.f) v = 0.f;
  meanArr[idx] = m;
  istdArr[idx] = rsqrtf(v + EPSV);
}

// ---------------------------------------------------------------------------
// Weight pre-pack: enc/aenc/c1 -> transposed bf16 hi/lo pairs (fp32-quality);
// key/sel/val -> transposed single bf16 (measured: no absmax impact, R5).
// ---------------------------------------------------------------------------
__device__ __forceinline__ void packpair(float w, u16* __restrict__ dh,
                                         u16* __restrict__ dl, int i){
  u16 h = f2bf(w);
  dh[i] = h;
  dl[i] = f2bf(w - bf2f(h));
}

__global__ __launch_bounds__(256) void k_pack(
    const float* __restrict__ enc_w, const float* __restrict__ aenc_w,
    const float* __restrict__ key_w, const float* __restrict__ sel_w,
    const float* __restrict__ val_w, const float* __restrict__ c1_w,
    u16* __restrict__ encH, u16* __restrict__ encL,
    u16* __restrict__ aencH, u16* __restrict__ aencL,
    u16* __restrict__ keyH, u16* __restrict__ selH, u16* __restrict__ valH,
    u16* __restrict__ c1H, u16* __restrict__ c1L)
{
  int i = blockIdx.x * 256 + threadIdx.x;
  const int S0 = A_N * H_N * ENC_KP;   // 196608
  const int S1 = A_N * H_N * OUT_N;    // 32768
  const int S2 = KD_N * H_N;           // 16384
  const int S5 = A_N * H_N * CIN_N;    // 262144
  if (i < S0){
    int a = i / (H_N * ENC_KP); int r = i % (H_N * ENC_KP);
    int n = r / ENC_KP; int k = r % ENC_KP;
    float v = (k < SAF) ? enc_w[((size_t)a * SAF + k) * H_N + n] : 0.f;
    packpair(v, encH, encL, i);
    return;
  }
  i -= S0;
  if (i < S1){
    int a = i / (H_N * OUT_N); int r = i % (H_N * OUT_N);
    int n = r / OUT_N; int k = r % OUT_N;
    packpair(aenc_w[((size_t)a * OUT_N + k) * H_N + n], aencH, aencL, i);
    return;
  }
  i -= S1;
  if (i < 3 * S2){
    int which = i / S2; int j = i % S2;
    int n = j / H_N, k = j % H_N;
    const float* w = (which == 0) ? key_w : ((which == 1) ? sel_w : val_w);
    u16* dh = (which == 0) ? keyH : ((which == 1) ? selH : valH);
    dh[j] = f2bf(w[(((size_t)(n >> 5)) * H_N + k) * D_N + (n & 31)]);
    return;
  }
  i -= 3 * S2;
  if (i < S5){
    int a = i / (H_N * CIN_N); int r = i % (H_N * CIN_N);
    int n = r / CIN_N; int k = r % CIN_N;
    packpair(c1_w[((size_t)a * CIN_N + k) * H_N + n], c1H, c1L, i);
  }
}
#define PACK_TOTAL (A_N*H_N*ENC_KP + A_N*H_N*OUT_N + 3*KD_N*H_N + A_N*H_N*CIN_N)

// ---------------------------------------------------------------------------
// Merged encoder kernel. role = blockIdx.x & 1 (interleaved for CU mixing):
//  role 0: sa_enc = lrelu(BN(concat)@enc_w+enc_b) [3-term]; sels = sa_enc@sel_w
//  role 1: a_enc = lrelu(BN(actions)@aenc_w+aenc_b) [3-term];
//          keys = a_enc@key_w (scalar store); vals = lrelu(a_enc@val_w+val_b)
// All K-loops register-prefetch the next tile (loads in flight during MFMA).
// Shared 46.6 KB LDS arena -> 3 blocks/CU for both roles.
// frag layouts (verified m89/m91): A[m=lane&15][k=quad*8+j]; C col=lane&15,
// row=quad*4+reg. Strides 40/136 u16 are 16B-multiples => free 2-way only.
// ---------------------------------------------------------------------------
__global__ __launch_bounds__(256, 3) void k_encoders(
    const float* __restrict__ states, const float* __restrict__ actions,
    const float* __restrict__ mean, const float* __restrict__ istd,
    const u16* __restrict__ encH, const u16* __restrict__ encL,
    const float* __restrict__ enc_b, const u16* __restrict__ selH,
    const u16* __restrict__ aencH, const u16* __restrict__ aencL,
    const float* __restrict__ aenc_b,
    const u16* __restrict__ keyH, const u16* __restrict__ valH,
    const float* __restrict__ val_b,
    u16* __restrict__ sa_enc, u16* __restrict__ sels,
    u16* __restrict__ keys, u16* __restrict__ vals)
{
  int role = blockIdx.x & 1;
  int row0 = (blockIdx.x >> 1) * 128;
  int a = blockIdx.y;
  int t = threadIdx.x;
  int lane = t & 63, wave = t >> 6, l16 = lane & 15, quad = lane >> 4;
  __shared__ __align__(16) u16 S[22528];
  __shared__ __align__(16) float scsh[384];

  floatx4 acc[2][8];
  #pragma unroll
  for (int mt = 0; mt < 2; ++mt)
    #pragma unroll
    for (int nt = 0; nt < 8; ++nt) acc[mt][nt] = (floatx4){0.f,0.f,0.f,0.f};

  if (role == 0){
    // ================== role 0: enc + sels ==================
    u16* Wh = S;            // [128][40]
    u16* Wl = S + 5120;
    u16* Xh = S + 10240;
    u16* Xl = S + 15360;
    u16* T  = S;            // [128][136] (phase 2)
    u16* Ws2 = S + 17408;   // [128][40]  (phase 2 sel weights)
    float* sc = scsh; float* sh = scsh + 192;

    if (t < 192){
      float m = 0.f, s = 0.f;
      if (t < SAF){ m = mean[a * SAF + t]; s = istd[a * SAF + t]; }
      sc[t] = s; sh[t] = -m * s;
    }
    const u16* wbh = encH + (size_t)a * H_N * ENC_KP;
    const u16* wbl = encL + (size_t)a * H_N * ENC_KP;
    __syncthreads();

    // prefetch registers
    uint4 pwh[2], pwl[2]; float4 px[4];
    auto loadW = [&](int k0){
      #pragma unroll
      for (int i = 0; i < 2; ++i){
        int c = t + i * 256; int n = c >> 2, off = (c & 3) * 8;
        pwh[i] = *(const uint4*)(wbh + (size_t)n * ENC_KP + k0 + off);
        pwl[i] = *(const uint4*)(wbl + (size_t)n * ENC_KP + k0 + off);
      }
    };
    auto loadX = [&](int k0){
      #pragma unroll
      for (int i = 0; i < 4; ++i){
        int c = t + i * 256; int r = c >> 3, kc = (c & 7) * 4, f = k0 + kc;
        size_t row = (size_t)a * B_N + row0 + r;
        float4 v = {0.f, 0.f, 0.f, 0.f};
        if (f < IN_N)     v = *(const float4*)(states + row * IN_N + f);
        else if (f < SAF) v = *(const float4*)(actions + row * OUT_N + (f - IN_N));
        px[i] = v;
      }
    };
    auto storeTiles = [&](int k0){
      #pragma unroll
      for (int i = 0; i < 2; ++i){
        int c = t + i * 256; int n = c >> 2, off = (c & 3) * 8;
        *(uint4*)&Wh[n * 40 + off] = pwh[i];
        *(uint4*)&Wl[n * 40 + off] = pwl[i];
      }
      #pragma unroll
      for (int i = 0; i < 4; ++i){
        int c = t + i * 256; int r = c >> 3, kc = (c & 7) * 4, f = k0 + kc;
        float4 v = px[i];
        float4 scv = *(const float4*)&sc[f];
        float4 shv = *(const float4*)&sh[f];
        float x0 = fmaf(v.x, scv.x, shv.x), x1 = fmaf(v.y, scv.y, shv.y);
        float x2 = fmaf(v.z, scv.z, shv.z), x3 = fmaf(v.w, scv.w, shv.w);
        u16 h0 = f2bf(x0), h1 = f2bf(x1), h2 = f2bf(x2), h3 = f2bf(x3);
        *(u32*)&Xh[r * 40 + kc]     = (u32)h0 | ((u32)h1 << 16);
        *(u32*)&Xh[r * 40 + kc + 2] = (u32)h2 | ((u32)h3 << 16);
        u16 l0 = f2bf(x0 - bf2f(h0)), l1 = f2bf(x1 - bf2f(h1));
        u16 l2 = f2bf(x2 - bf2f(h2)), l3 = f2bf(x3 - bf2f(h3));
        *(u32*)&Xl[r * 40 + kc]     = (u32)l0 | ((u32)l1 << 16);
        *(u32*)&Xl[r * 40 + kc + 2] = (u32)l2 | ((u32)l3 << 16);
      }
    };

    // ---- phase 1: enc GEMM (3-term split), BK=32, software-pipelined ----
    loadW(0); loadX(0);
    for (int k0 = 0; k0 < ENC_KP; k0 += 32){
      storeTiles(k0);
      __syncthreads();
      if (k0 + 32 < ENC_KP){ loadW(k0 + 32); loadX(k0 + 32); }
      {
        short8 ah[2], al[2], bh[8], bl[8];
        #pragma unroll
        for (int mt = 0; mt < 2; ++mt){
          int rr = (wave * 32 + mt * 16 + l16) * 40 + quad * 8;
          ah[mt] = *(const short8*)&Xh[rr];
          al[mt] = *(const short8*)&Xl[rr];
        }
        #pragma unroll
        for (int nt = 0; nt < 8; ++nt){
          int rr = (nt * 16 + l16) * 40 + quad * 8;
          bh[nt] = *(const short8*)&Wh[rr];
          bl[nt] = *(const short8*)&Wl[rr];
        }
        #pragma unroll
        for (int mt = 0; mt < 2; ++mt)
          #pragma unroll
          for (int nt = 0; nt < 8; ++nt){
            acc[mt][nt] = __builtin_amdgcn_mfma_f32_16x16x32_bf16(ah[mt], bh[nt], acc[mt][nt], 0,0,0);
            acc[mt][nt] = __builtin_amdgcn_mfma_f32_16x16x32_bf16(ah[mt], bl[nt], acc[mt][nt], 0,0,0);
            acc[mt][nt] = __builtin_amdgcn_mfma_f32_16x16x32_bf16(al[mt], bh[nt], acc[mt][nt], 0,0,0);
          }
      }
      __syncthreads();
    }

    // phase-1 epilogue: lrelu+bias -> bf16 tile T
    {
      float bv[8];
      #pragma unroll
      for (int nt = 0; nt < 8; ++nt) bv[nt] = enc_b[a * H_N + nt * 16 + l16];
      #pragma unroll
      for (int mt = 0; mt < 2; ++mt)
        #pragma unroll
        for (int nt = 0; nt < 8; ++nt)
          #pragma unroll
          for (int r = 0; r < 4; ++r){
            int rl = wave * 32 + mt * 16 + quad * 4 + r;
            T[rl * 136 + nt * 16 + l16] = f2bf(lrelu(acc[mt][nt][r] + bv[nt]));
          }
    }
    __syncthreads();
    for (int c = t; c < 2048; c += 256){
      int row = c >> 4, col8 = (c & 15) * 8;
      *(uint4*)(sa_enc + ((size_t)a * B_N + row0 + row) * H_N + col8) =
          *(const uint4*)&T[row * 136 + col8];
    }

    // ---- phase 2: sels = T @ selT (single-term), BK=32, pipelined ----
    #pragma unroll
    for (int mt = 0; mt < 2; ++mt)
      #pragma unroll
      for (int nt = 0; nt < 8; ++nt) acc[mt][nt] = (floatx4){0.f,0.f,0.f,0.f};
    uint4 ps[2];
    auto loadS = [&](int k0){
      #pragma unroll
      for (int i = 0; i < 2; ++i){
        int c = t + i * 256; int n = c >> 2, off = (c & 3) * 8;
        ps[i] = *(const uint4*)(selH + (size_t)n * H_N + k0 + off);
      }
    };
    loadS(0);
    for (int k0 = 0; k0 < H_N; k0 += 32){
      #pragma unroll
      for (int i = 0; i < 2; ++i){
        int c = t + i * 256; int n = c >> 2, off = (c & 3) * 8;
        *(uint4*)&Ws2[n * 40 + off] = ps[i];
      }
      __syncthreads();
      if (k0 + 32 < H_N) loadS(k0 + 32);
      {
        short8 ah[2], bh[8];
        #pragma unroll
        for (int mt = 0; mt < 2; ++mt)
          ah[mt] = *(const short8*)&T[(wave * 32 + mt * 16 + l16) * 136 + k0 + quad * 8];
        #pragma unroll
        for (int nt = 0; nt < 8; ++nt)
          bh[nt] = *(const short8*)&Ws2[(nt * 16 + l16) * 40 + quad * 8];
        #pragma unroll
        for (int mt = 0; mt < 2; ++mt)
          #pragma unroll
          for (int nt = 0; nt < 8; ++nt)
            acc[mt][nt] = __builtin_amdgcn_mfma_f32_16x16x32_bf16(ah[mt], bh[nt], acc[mt][nt], 0,0,0);
      }
      __syncthreads();
    }
    #pragma unroll
    for (int mt = 0; mt < 2; ++mt)
      #pragma unroll
      for (int nt = 0; nt < 8; ++nt)
        #pragma unroll
        for (int r = 0; r < 4; ++r){
          int rl = wave * 32 + mt * 16 + quad * 4 + r;
          T[rl * 136 + nt * 16 + l16] = f2bf(acc[mt][nt][r]);
        }
    __syncthreads();
    for (int c = t; c < 2048; c += 256){
      int row = c >> 4, col8 = (c & 15) * 8;
      *(uint4*)(sels + ((size_t)a * B_N + row0 + row) * H_N + col8) =
          *(const uint4*)&T[row * 136 + col8];
    }

  } else {
    // ================== role 1: aenc + keys + vals ==================
    u16* T = S;             // [128][136] a_enc tile; later vals tile
    u16* W2 = S + 17408;    // [128][40] phase-2 weight staging
    float* sc = scsh; float* sh = scsh + 32;

    if (t < 32){
      float m = mean[a * SAF + 128 + t], s = istd[a * SAF + 128 + t];
      sc[t] = s; sh[t] = -m * s;
    }
    __syncthreads();

    // ---- phase 1: aenc GEMM, K=32 single tile (stride 40) ----
    {
      u16* Wh1 = S;  u16* Wl1 = S + 5120;
      u16* Xh = S + 10240; u16* Xl = S + 15360;
      const u16* wbh = aencH + (size_t)a * H_N * OUT_N;
      const u16* wbl = aencL + (size_t)a * H_N * OUT_N;
      for (int c = t; c < 512; c += 256){
        int n = c >> 2, off = (c & 3) * 8;
        *(uint4*)&Wh1[n * 40 + off] = *(const uint4*)(wbh + (size_t)n * OUT_N + off);
        *(uint4*)&Wl1[n * 40 + off] = *(const uint4*)(wbl + (size_t)n * OUT_N + off);
      }
      for (int c = t; c < 1024; c += 256){
        int r = c >> 3, kc = (c & 7) * 4;
        size_t row = (size_t)a * B_N + row0 + r;
        float4 v = *(const float4*)(actions + row * OUT_N + kc);
        float4 scv = *(const float4*)&sc[kc];
        float4 shv = *(const float4*)&sh[kc];
        float x0 = fmaf(v.x, scv.x, shv.x), x1 = fmaf(v.y, scv.y, shv.y);
        float x2 = fmaf(v.z, scv.z, shv.z), x3 = fmaf(v.w, scv.w, shv.w);
        u16 h0 = f2bf(x0), h1 = f2bf(x1), h2 = f2bf(x2), h3 = f2bf(x3);
        *(u32*)&Xh[r * 40 + kc]     = (u32)h0 | ((u32)h1 << 16);
        *(u32*)&Xh[r * 40 + kc + 2] = (u32)h2 | ((u32)h3 << 16);
        u16 l0 = f2bf(x0 - bf2f(h0)), l1 = f2bf(x1 - bf2f(h1));
        u16 l2 = f2bf(x2 - bf2f(h2)), l3 = f2bf(x3 - bf2f(h3));
        *(u32*)&Xl[r * 40 + kc]     = (u32)l0 | ((u32)l1 << 16);
        *(u32*)&Xl[r * 40 + kc + 2] = (u32)l2 | ((u32)l3 << 16);
      }
      __syncthreads();
      short8 ah[2], al[2], bh[8], bl[8];
      #pragma unroll
      for (int mt = 0; mt < 2; ++mt){
        int rr = (wave * 32 + mt * 16 + l16) * 40 + quad * 8;
        ah[mt] = *(const short8*)&Xh[rr];
        al[mt] = *(const short8*)&Xl[rr];
      }
      #pragma unroll
      for (int nt = 0; nt < 8; ++nt){
        int rr = (nt * 16 + l16) * 40 + quad * 8;
        bh[nt] = *(const short8*)&Wh1[rr];
        bl[nt] = *(const short8*)&Wl1[rr];
      }
      #pragma unroll
      for (int mt = 0; mt < 2; ++mt)
        #pragma unroll
        for (int nt = 0; nt < 8; ++nt){
          acc[mt][nt] = __builtin_amdgcn_mfma_f32_16x16x32_bf16(ah[mt], bh[nt], acc[mt][nt], 0,0,0);
          acc[mt][nt] = __builtin_amdgcn_mfma_f32_16x16x32_bf16(ah[mt], bl[nt], acc[mt][nt], 0,0,0);
          acc[mt][nt] = __builtin_amdgcn_mfma_f32_16x16x32_bf16(al[mt], bh[nt], acc[mt][nt], 0,0,0);
        }
      __syncthreads();
    }
    // a_enc -> LDS tile T
    {
      float bv[8];
      #pragma unroll
      for (int nt = 0; nt < 8; ++nt) bv[nt] = aenc_b[a * H_N + nt * 16 + l16];
      #pragma unroll
      for (int mt = 0; mt < 2; ++mt)
        #pragma unroll
        for (int nt = 0; nt < 8; ++nt){
          #pragma unroll
          for (int r = 0; r < 4; ++r){
            int rl = wave * 32 + mt * 16 + quad * 4 + r;
            T[rl * 136 + nt * 16 + l16] = f2bf(lrelu(acc[mt][nt][r] + bv[nt]));
          }
        }
    }

    // ---- phases 2a/2b: keys then vals, BK=32, pipelined weight staging ----
    uint4 pw[2];
    auto loadW2 = [&](const u16* wsrc, int k0){
      #pragma unroll
      for (int i = 0; i < 2; ++i){
        int c = t + i * 256; int n = c >> 2, off = (c & 3) * 8;
        pw[i] = *(const uint4*)(wsrc + (size_t)n * H_N + k0 + off);
      }
    };
    #pragma unroll
    for (int ph = 0; ph < 2; ++ph){
      const u16* wsrc = (ph == 0) ? keyH : valH;
      #pragma unroll
      for (int mt = 0; mt < 2; ++mt)
        #pragma unroll
        for (int nt = 0; nt < 8; ++nt) acc[mt][nt] = (floatx4){0.f,0.f,0.f,0.f};
      loadW2(wsrc, 0);
      for (int k0 = 0; k0 < H_N; k0 += 32){
        #pragma unroll
        for (int i = 0; i < 2; ++i){
          int c = t + i * 256; int n = c >> 2, off = (c & 3) * 8;
          *(uint4*)&W2[n * 40 + off] = pw[i];
        }
        __syncthreads();   // also covers T visibility on first iteration
        if (k0 + 32 < H_N) loadW2(wsrc, k0 + 32);
        {
          short8 ah[2], bh[8];
          #pragma unroll
          for (int mt = 0; mt < 2; ++mt)
            ah[mt] = *(const short8*)&T[(wave * 32 + mt * 16 + l16) * 136 + k0 + quad * 8];
          #pragma unroll
          for (int nt = 0; nt < 8; ++nt)
            bh[nt] = *(const short8*)&W2[(nt * 16 + l16) * 40 + quad * 8];
          #pragma unroll
          for (int mt = 0; mt < 2; ++mt)
            #pragma unroll
            for (int nt = 0; nt < 8; ++nt)
              acc[mt][nt] = __builtin_amdgcn_mfma_f32_16x16x32_bf16(ah[mt], bh[nt], acc[mt][nt], 0,0,0);
        }
        __syncthreads();
      }
      if (ph == 0){
        // keys: scalar stores straight from acc (T still holds a_enc)
        #pragma unroll
        for (int mt = 0; mt < 2; ++mt)
          #pragma unroll
          for (int nt = 0; nt < 8; ++nt)
            #pragma unroll
            for (int r = 0; r < 4; ++r){
              int rl = wave * 32 + mt * 16 + quad * 4 + r;
              keys[((size_t)a * B_N + row0 + rl) * H_N + nt * 16 + l16] =
                  f2bf(acc[mt][nt][r]);
            }
      }
    }
    // vals epilogue: overwrite T (a_enc dead), store vectorized
    {
      float bv[8];
      #pragma unroll
      for (int nt = 0; nt < 8; ++nt) bv[nt] = val_b[nt * 16 + l16];
      #pragma unroll
      for (int mt = 0; mt < 2; ++mt)
        #pragma unroll
        for (int nt = 0; nt < 8; ++nt)
          #pragma unroll
          for (int r = 0; r < 4; ++r){
            int rl = wave * 32 + mt * 16 + quad * 4 + r;
            T[rl * 136 + nt * 16 + l16] = f2bf(lrelu(acc[mt][nt][r] + bv[nt]));
          }
    }
    __syncthreads();
    for (int c = t; c < 2048; c += 256){
      int row = c >> 4, col8 = (c & 15) * 8;
      *(uint4*)(vals + ((size_t)a * B_N + row0 + row) * H_N + col8) =
          *(const uint4*)&T[row * 136 + col8];
    }
  }
}

// ---------------------------------------------------------------------------
// Attention: block = 8 b-rows, all agents/heads in LDS. `other` may alias
// `keys` (all global reads complete before __syncthreads; rows disjoint
// across blocks).
// ---------------------------------------------------------------------------
__global__ __launch_bounds__(256) void k_attn(
    const u16* __restrict__ sels, const u16* __restrict__ keys,
    const u16* __restrict__ vals, u16* __restrict__ other)
{
  int b0 = blockIdx.x * 8;
  int t = threadIdx.x;
  __shared__ __align__(16) u16 sS[8192], sK[8192], sV[8192];
  u32* dS = (u32*)sS; u32* dK = (u32*)sK; u32* dV = (u32*)sV;
  #pragma unroll
  for (int a = 0; a < 8; ++a){
    size_t go = ((size_t)a * B_N + b0) * KD_N;
    const u32* gs = (const u32*)(sels + go);
    const u32* gk = (const u32*)(keys + go);
    const u32* gv = (const u32*)(vals + go);
    dS[a * 512 + t] = gs[t]; dS[a * 512 + 256 + t] = gs[256 + t];
    dK[a * 512 + t] = gk[t]; dK[a * 512 + 256 + t] = gk[256 + t];
    dV[a * 512 + t] = gv[t]; dV[a * 512 + 256 + t] = gv[256 + t];
  }
  __syncthreads();
  int i = t & 7, p = t >> 3;
  int k = p & 3, bl = p >> 2;
  int base_i = (i * 8 + bl) * 128 + k * 32;
  float si[32];
  {
    const u32* S32 = (const u32*)&sS[base_i];
    #pragma unroll
    for (int d2 = 0; d2 < 16; ++d2){
      u32 u = S32[d2];
      si[2 * d2] = bf_lo(u); si[2 * d2 + 1] = bf_hi(u);
    }
  }
  float lg[8];
  #pragma unroll
  for (int j = 0; j < 8; ++j){
    const u32* K32 = (const u32*)&sK[(j * 8 + bl) * 128 + k * 32];
    float acc = 0.f;
    #pragma unroll
    for (int d2 = 0; d2 < 16; ++d2){
      u32 u = K32[d2];
      acc = fmaf(si[2 * d2], bf_lo(u), acc);
      acc = fmaf(si[2 * d2 + 1], bf_hi(u), acc);
    }
    lg[j] = acc * 0.17677669529663689f;
  }
  float mx = -3.0e38f;
  #pragma unroll
  for (int j = 0; j < 8; ++j) if (j != i) mx = fmaxf(mx, lg[j]);
  float pe[8], se = 0.f;
  #pragma unroll
  for (int j = 0; j < 8; ++j){
    pe[j] = (j == i) ? 0.f : __expf(lg[j] - mx);
    se += pe[j];
  }
  float inv = 1.f / se;
  #pragma unroll
  for (int j = 0; j < 8; ++j) pe[j] *= inv;
  __align__(16) u16 ob[32];
  #pragma unroll
  for (int d2 = 0; d2 < 16; ++d2){
    float acc0 = 0.f, acc1 = 0.f;
    #pragma unroll
    for (int j = 0; j < 8; ++j){
      u32 u = *(const u32*)&sV[(j * 8 + bl) * 128 + k * 32 + 2 * d2];
      acc0 = fmaf(pe[j], bf_lo(u), acc0);
      acc1 = fmaf(pe[j], bf_hi(u), acc1);
    }
    ob[2 * d2] = f2bf(acc0); ob[2 * d2 + 1] = f2bf(acc1);
  }
  uint4* dst = (uint4*)(other + ((size_t)i * B_N + (b0 + bl)) * KD_N + k * 32);
  const uint4* s4 = (const uint4*)ob;
  #pragma unroll
  for (int c = 0; c < 4; ++c) dst[c] = s4[c];
}

// ---------------------------------------------------------------------------
// Critic: h = lrelu([sa_enc|other] @ c1_w + c1_b); q = h . c2_w + c2_b
// 2-term hi/lo, K=256, BK=32, register-prefetched pipeline.
// ---------------------------------------------------------------------------
__global__ __launch_bounds__(256, 3) void k_critic(
    const u16* __restrict__ sa_enc, const u16* __restrict__ other,
    const u16* __restrict__ c1H, const u16* __restrict__ c1L,
    const float* __restrict__ c1_b,
    const float* __restrict__ c2w, const float* __restrict__ c2b,
    float* __restrict__ qout)
{
  int a = blockIdx.y; int row0 = blockIdx.x * 128; int t = threadIdx.x;
  int lane = t & 63, wave = t >> 6, l16 = lane & 15, quad = lane >> 4;
  __shared__ __align__(16) u16 Xs[5120];
  __shared__ __align__(16) u16 Wh[5120];
  __shared__ __align__(16) u16 Wl[5120];
  floatx4 acc[2][8];
  #pragma unroll
  for (int mt = 0; mt < 2; ++mt)
    #pragma unroll
    for (int nt = 0; nt < 8; ++nt) acc[mt][nt] = (floatx4){0.f,0.f,0.f,0.f};
  const u16* wbh = c1H + (size_t)a * H_N * CIN_N;
  const u16* wbl = c1L + (size_t)a * H_N * CIN_N;

  uint4 pwh[2], pwl[2], pxr[2];
  auto ldW = [&](int k0){
    #pragma unroll
    for (int i = 0; i < 2; ++i){
      int c = t + i * 256; int n = c >> 2, off = (c & 3) * 8;
      pwh[i] = *(const uint4*)(wbh + (size_t)n * CIN_N + k0 + off);
      pwl[i] = *(const uint4*)(wbl + (size_t)n * CIN_N + k0 + off);
    }
  };
  auto ldX = [&](int k0){
    #pragma unroll
    for (int i = 0; i < 2; ++i){
      int c = t + i * 256; int r = c >> 2, off = (c & 3) * 8;
      int fo = k0 + off;
      const u16* src = sa_enc;
      if (fo >= H_N){ src = other; fo -= H_N; }
      pxr[i] = *(const uint4*)(src + ((size_t)a * B_N + row0 + r) * H_N + fo);
    }
  };
  ldW(0); ldX(0);
  for (int k0 = 0; k0 < CIN_N; k0 += 32){
    #pragma unroll
    for (int i = 0; i < 2; ++i){
      int c = t + i * 256; int n = c >> 2, off = (c & 3) * 8;
      *(uint4*)&Wh[n * 40 + off] = pwh[i];
      *(uint4*)&Wl[n * 40 + off] = pwl[i];
      *(uint4*)&Xs[n * 40 + off] = pxr[i];
    }
    __syncthreads();
    if (k0 + 32 < CIN_N){ ldW(k0 + 32); ldX(k0 + 32); }
    {
      short8 ah[2], bh[8], bl[8];
      #pragma unroll
      for (int mt = 0; mt < 2; ++mt)
        ah[mt] = *(const short8*)&Xs[(wave * 32 + mt * 16 + l16) * 40 + quad * 8];
      #pragma unroll
      for (int nt = 0; nt < 8; ++nt){
        int rr = (nt * 16 + l16) * 40 + quad * 8;
        bh[nt] = *(const short8*)&Wh[rr];
        bl[nt] = *(const short8*)&Wl[rr];
      }
      #pragma unroll
      for (int mt = 0; mt < 2; ++mt)
        #pragma unroll
        for (int nt = 0; nt < 8; ++nt){
          acc[mt][nt] = __builtin_amdgcn_mfma_f32_16x16x32_bf16(ah[mt], bh[nt], acc[mt][nt], 0,0,0);
          acc[mt][nt] = __builtin_amdgcn_mfma_f32_16x16x32_bf16(ah[mt], bl[nt], acc[mt][nt], 0,0,0);
        }
    }
    __syncthreads();
  }

  float c2r[8], bv[8];
  #pragma unroll
  for (int nt = 0; nt < 8; ++nt){
    c2r[nt] = c2w[a * H_N + nt * 16 + l16];
    bv[nt]  = c1_b[a * H_N + nt * 16 + l16];
  }
  #pragma unroll
  for (int mt = 0; mt < 2; ++mt){
    #pragma unroll
    for (int r = 0; r < 4; ++r){
      float s = 0.f;
      #pragma unroll
      for (int nt = 0; nt < 8; ++nt){
        float h = lrelu(acc[mt][nt][r] + bv[nt]);
        s = fmaf(h, c2r[nt], s);
      }
      s += __shfl_xor(s, 1);
      s += __shfl_xor(s, 2);
      s += __shfl_xor(s, 4);
      s += __shfl_xor(s, 8);
      if (l16 == 0){
        int row = row0 + wave * 32 + mt * 16 + quad * 4 + r;
        qout[(size_t)a * B_N + row] = s + c2b[a];
      }
    }
  }
}

// ---------------------------------------------------------------------------
extern "C" void kernel_launch(void* const* d_in, const int* in_sizes, int n_in,
                              void* d_out, int out_size, void* d_ws, size_t ws_size,
                              hipStream_t stream)
{
  const float* states  = (const float*)d_in[0];
  const float* actions = (const float*)d_in[1];
  const float* enc_w   = (const float*)d_in[2];
  const float* enc_b   = (const float*)d_in[3];
  const float* aenc_w  = (const float*)d_in[4];
  const float* aenc_b  = (const float*)d_in[5];
  const float* key_w   = (const float*)d_in[6];
  const float* sel_w   = (const float*)d_in[7];
  const float* val_w   = (const float*)d_in[8];
  const float* val_b   = (const float*)d_in[9];
  const float* c1_w    = (const float*)d_in[10];
  const float* c1_b    = (const float*)d_in[11];
  const float* c2_w    = (const float*)d_in[12];
  const float* c2_b    = (const float*)d_in[13];
  float* q = (float*)d_out;

  char* ws = (char*)d_ws;
  // Pack region [0, 1,015,808) overlaps stats partials [0, 1,310,720):
  // stats/finalize consume `part` before k_pack overwrites (sequential stream).
  u16* encH  = (u16*)(ws + 0);          // 393216 B
  u16* encL  = (u16*)(ws + 393216);     // 393216 B
  u16* aencH = (u16*)(ws + 786432);     //  65536 B
  u16* aencL = (u16*)(ws + 851968);     //  65536 B
  u16* keyH  = (u16*)(ws + 917504);     //  32768 B
  u16* selH  = (u16*)(ws + 950272);     //  32768 B
  u16* valH  = (u16*)(ws + 983040);     //  32768 B -> ends 1,015,808
  float* part    = (float*)ws;          // 1,310,720 B (dead after finalize)
  float* meanArr = (float*)(ws + 1310720);
  float* istdArr = (float*)(ws + 1315840);
  u16* c1H = (u16*)(ws + 1320960);      // 524288 B
  u16* c1L = (u16*)(ws + 1845248);      // 524288 B -> ends 2,369,536
  const size_t ibase = 4194304;
  const size_t BUF = (size_t)A_N * B_N * 128 * 2;   // 64 MB
  u16* sa_enc = (u16*)(ws + ibase);
  u16* sels   = (u16*)(ws + ibase + BUF);
  u16* keys   = (u16*)(ws + ibase + 2 * BUF);       // keys, later `other`
  u16* vals   = (u16*)(ws + ibase + 3 * BUF);

  k_stats<<<dim3(CHUNKS, A_N), 256, 0, stream>>>(states, actions, part);
  k_finalize<<<(A_N * SAF + 255) / 256, 256, 0, stream>>>(part, meanArr, istdArr);
  k_pack<<<(PACK_TOTAL + 255) / 256, 256, 0, stream>>>(
      enc_w, aenc_w, key_w, sel_w, val_w, c1_w,
      encH, encL, aencH, aencL, keyH, selH, valH, c1H, c1L);

  k_encoders<<<dim3(B_N / 128 * 2, A_N), 256, 0, stream>>>(
      states, actions, meanArr, istdArr,
      encH, encL, enc_b, selH,
      aencH, aencL, aenc_b, keyH, valH, val_b,
      sa_enc, sels, keys, vals);
  k_attn<<<B_N / 8, 256, 0, stream>>>(sels, keys, vals, keys);  // other -> keys
  k_critic<<<dim3(B_N / 128, A_N), 256, 0, stream>>>(
      sa_enc, keys, c1H, c1L, c1_b, c2_w, c2_b, q);
}

// Round 7
// 636.910 us; speedup vs baseline: 1.2060x; 1.2060x over previous
//
#include <hip/hip_runtime.h>
#include <hip/hip_bf16.h>
#include <stdint.h>

// Problem constants
#define A_N 8
#define B_N 32768
#define IN_N 128
#define OUT_N 32
#define SAF 160      // IN + OUT
#define H_N 128
#define D_N 32
#define KD_N 128     // K*D
#define CIN_N 256    // critic input = H + K*D
#define CHUNKS 128   // stats chunks over B
#define EPSV 1e-5f
#define ENC_KP 192   // enc K padded 160 -> 192 (packed layout; zero tile skipped)

typedef unsigned int u32;
typedef unsigned short u16;
typedef __attribute__((ext_vector_type(8))) short short8;    // 8 bf16 (4 VGPRs)
typedef __attribute__((ext_vector_type(4))) float floatx4;   // MFMA C/D

__device__ __forceinline__ float bf_lo(u32 u){ return __uint_as_float(u << 16); }
__device__ __forceinline__ float bf_hi(u32 u){ return __uint_as_float(u & 0xffff0000u); }
__device__ __forceinline__ float bf2f(u16 b){ return __uint_as_float(((u32)b) << 16); }
__device__ __forceinline__ u16 f2bf(float f){
  u32 u = __float_as_uint(f);
  return (u16)((u + 0x7fffu + ((u >> 16) & 1u)) >> 16);
}
__device__ __forceinline__ float lrelu(float x){ return x > 0.f ? x : 0.01f * x; }

// ---------------------------------------------------------------------------
// Stage 1: BN statistics (sum, sumsq) per (agent, feature).
// ---------------------------------------------------------------------------
__global__ __launch_bounds__(256) void k_stats(
    const float* __restrict__ states, const float* __restrict__ actions,
    float* __restrict__ part)
{
  int a = blockIdx.y;
  int chunk = blockIdx.x;
  int t = threadIdx.x;
  int r0 = chunk * (B_N / CHUNKS);   // 256 rows per chunk
  __shared__ float red[512];
  {
    int f = t & 127, half = t >> 7;
    const float* p = states + ((size_t)a * B_N + r0 + half) * IN_N + f;
    float s1 = 0.f, s2 = 0.f;
    for (int it = 0; it < 128; ++it){
      float v = p[(size_t)(2 * it) * IN_N];
      s1 += v; s2 += v * v;
    }
    red[t] = s1; red[256 + t] = s2;
    __syncthreads();
    if (t < 128){
      float a1 = red[t] + red[t + 128];
      float a2 = red[256 + t] + red[256 + t + 128];
      size_t o = (((size_t)a * CHUNKS + chunk) * SAF + t) * 2;
      part[o] = a1; part[o + 1] = a2;
    }
    __syncthreads();
  }
  {
    int f = t & 31, g = t >> 5;
    const float* p = actions + ((size_t)a * B_N + r0 + g) * OUT_N + f;
    float s1 = 0.f, s2 = 0.f;
    for (int it = 0; it < 32; ++it){
      float v = p[(size_t)(8 * it) * OUT_N];
      s1 += v; s2 += v * v;
    }
    red[t] = s1; red[256 + t] = s2;
    __syncthreads();
    if (t < 32){
      float a1 = 0.f, a2 = 0.f;
      #pragma unroll
      for (int gg = 0; gg < 8; ++gg){
        a1 += red[t + 32 * gg];
        a2 += red[256 + t + 32 * gg];
      }
      size_t o = (((size_t)a * CHUNKS + chunk) * SAF + 128 + t) * 2;
      part[o] = a1; part[o + 1] = a2;
    }
  }
}

__global__ void k_finalize(const float* __restrict__ part,
                           float* __restrict__ meanArr, float* __restrict__ istdArr)
{
  int idx = blockIdx.x * blockDim.x + threadIdx.x;
  if (idx >= A_N * SAF) return;
  int a = idx / SAF, f = idx % SAF;
  float s1 = 0.f, s2 = 0.f;
  for (int c = 0; c < CHUNKS; ++c){
    size_t o = (((size_t)a * CHUNKS + c) * SAF + f) * 2;
    s1 += part[o]; s2 += part[o + 1];
  }
  float m = s1 * (1.f / B_N);
  float v = s2 * (1.f / B_N) - m * m;
  if (v < 0.f) v = 0.f;
  meanArr[idx] = m;
  istdArr[idx] = rsqrtf(v + EPSV);
}

// ---------------------------------------------------------------------------
// Weight pre-pack: enc/aenc -> transposed bf16 hi/lo pairs (fp32-quality);
// key/sel/val/c1 -> transposed single bf16 (R5 measured: no absmax impact
// for key/sel/val; c1 1-term predicted +~1e-3).
// ---------------------------------------------------------------------------
__device__ __forceinline__ void packpair(float w, u16* __restrict__ dh,
                                         u16* __restrict__ dl, int i){
  u16 h = f2bf(w);
  dh[i] = h;
  dl[i] = f2bf(w - bf2f(h));
}

__global__ __launch_bounds__(256) void k_pack(
    const float* __restrict__ enc_w, const float* __restrict__ aenc_w,
    const float* __restrict__ key_w, const float* __restrict__ sel_w,
    const float* __restrict__ val_w, const float* __restrict__ c1_w,
    u16* __restrict__ encH, u16* __restrict__ encL,
    u16* __restrict__ aencH, u16* __restrict__ aencL,
    u16* __restrict__ keyH, u16* __restrict__ selH, u16* __restrict__ valH,
    u16* __restrict__ c1H)
{
  int i = blockIdx.x * 256 + threadIdx.x;
  const int S0 = A_N * H_N * ENC_KP;   // 196608
  const int S1 = A_N * H_N * OUT_N;    // 32768
  const int S2 = KD_N * H_N;           // 16384
  const int S5 = A_N * H_N * CIN_N;    // 262144
  if (i < S0){
    int a = i / (H_N * ENC_KP); int r = i % (H_N * ENC_KP);
    int n = r / ENC_KP; int k = r % ENC_KP;
    float v = (k < SAF) ? enc_w[((size_t)a * SAF + k) * H_N + n] : 0.f;
    packpair(v, encH, encL, i);
    return;
  }
  i -= S0;
  if (i < S1){
    int a = i / (H_N * OUT_N); int r = i % (H_N * OUT_N);
    int n = r / OUT_N; int k = r % OUT_N;
    packpair(aenc_w[((size_t)a * OUT_N + k) * H_N + n], aencH, aencL, i);
    return;
  }
  i -= S1;
  if (i < 3 * S2){
    int which = i / S2; int j = i % S2;
    int n = j / H_N, k = j % H_N;
    const float* w = (which == 0) ? key_w : ((which == 1) ? sel_w : val_w);
    u16* dh = (which == 0) ? keyH : ((which == 1) ? selH : valH);
    dh[j] = f2bf(w[(((size_t)(n >> 5)) * H_N + k) * D_N + (n & 31)]);
    return;
  }
  i -= 3 * S2;
  if (i < S5){
    int a = i / (H_N * CIN_N); int r = i % (H_N * CIN_N);
    int n = r / CIN_N; int k = r % CIN_N;
    c1H[i] = f2bf(c1_w[((size_t)a * CIN_N + k) * H_N + n]);
  }
}
#define PACK_TOTAL (A_N*H_N*ENC_KP + A_N*H_N*OUT_N + 3*KD_N*H_N + A_N*H_N*CIN_N)

// ---------------------------------------------------------------------------
// Fused kernel 1: sa_enc = lrelu(BN(concat)@enc_w+enc_b) [3-term, K=160];
//                 sels = sa_enc @ sel_w [1-term, K=128].
// Phase 1: X fragments built IN-REGISTER (per-lane float4 loads + BN + hi/lo
// split); W fragments loaded directly from L2-resident packed weights.
// Phase 2: A from LDS tile T (ds_read), B direct from global. No barriers
// inside any K-loop. Frag layouts verified m89/m91: A[m=lane&15][k=quad*8+j];
// C col=lane&15, row=quad*4+reg. T stride 136 u16 = 272B (16B-mult).
// ---------------------------------------------------------------------------
__global__ __launch_bounds__(256, 2) void k_enc_sel(
    const float* __restrict__ states, const float* __restrict__ actions,
    const float* __restrict__ mean, const float* __restrict__ istd,
    const u16* __restrict__ encH, const u16* __restrict__ encL,
    const float* __restrict__ enc_b, const u16* __restrict__ selH,
    u16* __restrict__ sa_enc, u16* __restrict__ sels)
{
  int a = blockIdx.y; int row0 = blockIdx.x * 128; int t = threadIdx.x;
  int lane = t & 63, wave = t >> 6, l16 = lane & 15, quad = lane >> 4;
  __shared__ __align__(16) u16 T[128 * 136];
  __shared__ __align__(16) float sc[192], sh[192];

  if (t < 192){
    float m = 0.f, s = 0.f;
    if (t < SAF){ m = mean[a * SAF + t]; s = istd[a * SAF + t]; }
    sc[t] = s; sh[t] = -m * s;
  }
  floatx4 acc[2][8];
  #pragma unroll
  for (int mt = 0; mt < 2; ++mt)
    #pragma unroll
    for (int nt = 0; nt < 8; ++nt) acc[mt][nt] = (floatx4){0.f,0.f,0.f,0.f};
  const u16* wbh = encH + (size_t)a * H_N * ENC_KP;
  const u16* wbl = encL + (size_t)a * H_N * ENC_KP;
  __syncthreads();

  // ---- phase 1: enc (3-term), K=160 (5 tiles), barrier-free ----
  #pragma unroll
  for (int kt = 0; kt < 5; ++kt){
    int k0 = kt * 32;
    int f0 = k0 + quad * 8;
    float scv[8], shv[8];
    *(float4*)&scv[0] = *(const float4*)&sc[f0];
    *(float4*)&scv[4] = *(const float4*)&sc[f0 + 4];
    *(float4*)&shv[0] = *(const float4*)&sh[f0];
    *(float4*)&shv[4] = *(const float4*)&sh[f0 + 4];
    short8 ah[2], al[2];
    #pragma unroll
    for (int mt = 0; mt < 2; ++mt){
      size_t row = (size_t)a * B_N + row0 + wave * 32 + mt * 16 + l16;
      float x[8];
      if (kt < 4){
        float4 v0 = *(const float4*)(states + row * IN_N + f0);
        float4 v1 = *(const float4*)(states + row * IN_N + f0 + 4);
        x[0]=v0.x; x[1]=v0.y; x[2]=v0.z; x[3]=v0.w;
        x[4]=v1.x; x[5]=v1.y; x[6]=v1.z; x[7]=v1.w;
      } else {
        int fo = f0 - IN_N;
        float4 v0 = *(const float4*)(actions + row * OUT_N + fo);
        float4 v1 = *(const float4*)(actions + row * OUT_N + fo + 4);
        x[0]=v0.x; x[1]=v0.y; x[2]=v0.z; x[3]=v0.w;
        x[4]=v1.x; x[5]=v1.y; x[6]=v1.z; x[7]=v1.w;
      }
      short8 hv, lv;
      #pragma unroll
      for (int e = 0; e < 8; ++e){
        float xx = fmaf(x[e], scv[e], shv[e]);
        u16 hb = f2bf(xx);
        hv[e] = (short)hb;
        lv[e] = (short)f2bf(xx - bf2f(hb));
      }
      ah[mt] = hv; al[mt] = lv;
    }
    short8 bh[8], bl[8];
    #pragma unroll
    for (int nt = 0; nt < 8; ++nt){
      size_t wo = (size_t)(nt * 16 + l16) * ENC_KP + f0;
      bh[nt] = *(const short8*)(wbh + wo);
      bl[nt] = *(const short8*)(wbl + wo);
    }
    #pragma unroll
    for (int mt = 0; mt < 2; ++mt)
      #pragma unroll
      for (int nt = 0; nt < 8; ++nt){
        acc[mt][nt] = __builtin_amdgcn_mfma_f32_16x16x32_bf16(ah[mt], bh[nt], acc[mt][nt], 0,0,0);
        acc[mt][nt] = __builtin_amdgcn_mfma_f32_16x16x32_bf16(ah[mt], bl[nt], acc[mt][nt], 0,0,0);
        acc[mt][nt] = __builtin_amdgcn_mfma_f32_16x16x32_bf16(al[mt], bh[nt], acc[mt][nt], 0,0,0);
      }
  }

  // phase-1 epilogue: lrelu+bias -> bf16 tile T
  {
    float bv[8];
    #pragma unroll
    for (int nt = 0; nt < 8; ++nt) bv[nt] = enc_b[a * H_N + nt * 16 + l16];
    #pragma unroll
    for (int mt = 0; mt < 2; ++mt)
      #pragma unroll
      for (int nt = 0; nt < 8; ++nt)
        #pragma unroll
        for (int r = 0; r < 4; ++r){
          int rl = wave * 32 + mt * 16 + quad * 4 + r;
          T[rl * 136 + nt * 16 + l16] = f2bf(lrelu(acc[mt][nt][r] + bv[nt]));
        }
  }
  __syncthreads();
  // vectorized sa_enc store from T
  for (int c = t; c < 2048; c += 256){
    int row = c >> 4, col8 = (c & 15) * 8;
    *(uint4*)(sa_enc + ((size_t)a * B_N + row0 + row) * H_N + col8) =
        *(const uint4*)&T[row * 136 + col8];
  }

  // ---- phase 2: sels = T @ selT (1-term), K=128, barrier-free ----
  #pragma unroll
  for (int mt = 0; mt < 2; ++mt)
    #pragma unroll
    for (int nt = 0; nt < 8; ++nt) acc[mt][nt] = (floatx4){0.f,0.f,0.f,0.f};
  #pragma unroll
  for (int kt = 0; kt < 4; ++kt){
    int f0 = kt * 32 + quad * 8;
    short8 aT[2], bw[8];
    #pragma unroll
    for (int mt = 0; mt < 2; ++mt)
      aT[mt] = *(const short8*)&T[(wave * 32 + mt * 16 + l16) * 136 + f0];
    #pragma unroll
    for (int nt = 0; nt < 8; ++nt)
      bw[nt] = *(const short8*)(selH + (size_t)(nt * 16 + l16) * H_N + f0);
    #pragma unroll
    for (int mt = 0; mt < 2; ++mt)
      #pragma unroll
      for (int nt = 0; nt < 8; ++nt)
        acc[mt][nt] = __builtin_amdgcn_mfma_f32_16x16x32_bf16(aT[mt], bw[nt], acc[mt][nt], 0,0,0);
  }
  __syncthreads();   // all waves done reading T
  #pragma unroll
  for (int mt = 0; mt < 2; ++mt)
    #pragma unroll
    for (int nt = 0; nt < 8; ++nt)
      #pragma unroll
      for (int r = 0; r < 4; ++r){
        int rl = wave * 32 + mt * 16 + quad * 4 + r;
        T[rl * 136 + nt * 16 + l16] = f2bf(acc[mt][nt][r]);
      }
  __syncthreads();
  for (int c = t; c < 2048; c += 256){
    int row = c >> 4, col8 = (c & 15) * 8;
    *(uint4*)(sels + ((size_t)a * B_N + row0 + row) * H_N + col8) =
        *(const uint4*)&T[row * 136 + col8];
  }
}

// ---------------------------------------------------------------------------
// Fused kernel 2: a_enc = lrelu(BN(actions)@aenc_w+aenc_b) [3-term, K=32];
//   keys = a_enc@key_w, vals = lrelu(a_enc@val_w+val_b) in ONE dual-acc
//   K-loop (B direct from global). a_enc never touches HBM.
// ---------------------------------------------------------------------------
__global__ __launch_bounds__(256, 2) void k_aenc_kv(
    const float* __restrict__ actions,
    const float* __restrict__ mean, const float* __restrict__ istd,
    const u16* __restrict__ aencH, const u16* __restrict__ aencL,
    const float* __restrict__ aenc_b,
    const u16* __restrict__ keyH, const u16* __restrict__ valH,
    const float* __restrict__ val_b,
    u16* __restrict__ keys, u16* __restrict__ vals)
{
  int a = blockIdx.y; int row0 = blockIdx.x * 128; int t = threadIdx.x;
  int lane = t & 63, wave = t >> 6, l16 = lane & 15, quad = lane >> 4;
  __shared__ __align__(16) u16 T[128 * 136];
  __shared__ __align__(16) float sc[32], sh[32];

  if (t < 32){
    float m = mean[a * SAF + 128 + t], s = istd[a * SAF + 128 + t];
    sc[t] = s; sh[t] = -m * s;
  }
  floatx4 accK[2][8], accV[2][8];
  #pragma unroll
  for (int mt = 0; mt < 2; ++mt)
    #pragma unroll
    for (int nt = 0; nt < 8; ++nt){
      accK[mt][nt] = (floatx4){0.f,0.f,0.f,0.f};
      accV[mt][nt] = (floatx4){0.f,0.f,0.f,0.f};
    }
  const u16* wbh = aencH + (size_t)a * H_N * OUT_N;
  const u16* wbl = aencL + (size_t)a * H_N * OUT_N;
  __syncthreads();

  // ---- phase 1: aenc (3-term), K=32 single tile, barrier-free ----
  {
    int f0 = quad * 8;
    float scv[8], shv[8];
    *(float4*)&scv[0] = *(const float4*)&sc[f0];
    *(float4*)&scv[4] = *(const float4*)&sc[f0 + 4];
    *(float4*)&shv[0] = *(const float4*)&sh[f0];
    *(float4*)&shv[4] = *(const float4*)&sh[f0 + 4];
    short8 ah[2], al[2];
    #pragma unroll
    for (int mt = 0; mt < 2; ++mt){
      size_t row = (size_t)a * B_N + row0 + wave * 32 + mt * 16 + l16;
      float4 v0 = *(const float4*)(actions + row * OUT_N + f0);
      float4 v1 = *(const float4*)(actions + row * OUT_N + f0 + 4);
      float x[8] = {v0.x, v0.y, v0.z, v0.w, v1.x, v1.y, v1.z, v1.w};
      short8 hv, lv;
      #pragma unroll
      for (int e = 0; e < 8; ++e){
        float xx = fmaf(x[e], scv[e], shv[e]);
        u16 hb = f2bf(xx);
        hv[e] = (short)hb;
        lv[e] = (short)f2bf(xx - bf2f(hb));
      }
      ah[mt] = hv; al[mt] = lv;
    }
    short8 bh[8], bl[8];
    #pragma unroll
    for (int nt = 0; nt < 8; ++nt){
      size_t wo = (size_t)(nt * 16 + l16) * OUT_N + f0;
      bh[nt] = *(const short8*)(wbh + wo);
      bl[nt] = *(const short8*)(wbl + wo);
    }
    #pragma unroll
    for (int mt = 0; mt < 2; ++mt)
      #pragma unroll
      for (int nt = 0; nt < 8; ++nt){
        accK[mt][nt] = __builtin_amdgcn_mfma_f32_16x16x32_bf16(ah[mt], bh[nt], accK[mt][nt], 0,0,0);
        accK[mt][nt] = __builtin_amdgcn_mfma_f32_16x16x32_bf16(ah[mt], bl[nt], accK[mt][nt], 0,0,0);
        accK[mt][nt] = __builtin_amdgcn_mfma_f32_16x16x32_bf16(al[mt], bh[nt], accK[mt][nt], 0,0,0);
      }
  }
  // a_enc -> T, zero accK
  {
    float bv[8];
    #pragma unroll
    for (int nt = 0; nt < 8; ++nt) bv[nt] = aenc_b[a * H_N + nt * 16 + l16];
    #pragma unroll
    for (int mt = 0; mt < 2; ++mt)
      #pragma unroll
      for (int nt = 0; nt < 8; ++nt){
        #pragma unroll
        for (int r = 0; r < 4; ++r){
          int rl = wave * 32 + mt * 16 + quad * 4 + r;
          T[rl * 136 + nt * 16 + l16] = f2bf(lrelu(accK[mt][nt][r] + bv[nt]));
        }
        accK[mt][nt] = (floatx4){0.f,0.f,0.f,0.f};
      }
  }
  __syncthreads();

  // ---- phase 2: dual-acc keys+vals, K=128, barrier-free ----
  #pragma unroll
  for (int kt = 0; kt < 4; ++kt){
    int f0 = kt * 32 + quad * 8;
    short8 aT[2], bk[8], bv2[8];
    #pragma unroll
    for (int mt = 0; mt < 2; ++mt)
      aT[mt] = *(const short8*)&T[(wave * 32 + mt * 16 + l16) * 136 + f0];
    #pragma unroll
    for (int nt = 0; nt < 8; ++nt){
      size_t wo = (size_t)(nt * 16 + l16) * H_N + f0;
      bk[nt]  = *(const short8*)(keyH + wo);
      bv2[nt] = *(const short8*)(valH + wo);
    }
    #pragma unroll
    for (int mt = 0; mt < 2; ++mt)
      #pragma unroll
      for (int nt = 0; nt < 8; ++nt){
        accK[mt][nt] = __builtin_amdgcn_mfma_f32_16x16x32_bf16(aT[mt], bk[nt],  accK[mt][nt], 0,0,0);
        accV[mt][nt] = __builtin_amdgcn_mfma_f32_16x16x32_bf16(aT[mt], bv2[nt], accV[mt][nt], 0,0,0);
      }
  }
  __syncthreads();   // all waves done reading T (a_enc dead)

  // vals -> T -> store
  {
    float bv[8];
    #pragma unroll
    for (int nt = 0; nt < 8; ++nt) bv[nt] = val_b[nt * 16 + l16];
    #pragma unroll
    for (int mt = 0; mt < 2; ++mt)
      #pragma unroll
      for (int nt = 0; nt < 8; ++nt)
        #pragma unroll
        for (int r = 0; r < 4; ++r){
          int rl = wave * 32 + mt * 16 + quad * 4 + r;
          T[rl * 136 + nt * 16 + l16] = f2bf(lrelu(accV[mt][nt][r] + bv[nt]));
        }
  }
  __syncthreads();
  for (int c = t; c < 2048; c += 256){
    int row = c >> 4, col8 = (c & 15) * 8;
    *(uint4*)(vals + ((size_t)a * B_N + row0 + row) * H_N + col8) =
        *(const uint4*)&T[row * 136 + col8];
  }
  __syncthreads();   // stores consumed T
  // keys -> T -> store
  #pragma unroll
  for (int mt = 0; mt < 2; ++mt)
    #pragma unroll
    for (int nt = 0; nt < 8; ++nt)
      #pragma unroll
      for (int r = 0; r < 4; ++r){
        int rl = wave * 32 + mt * 16 + quad * 4 + r;
        T[rl * 136 + nt * 16 + l16] = f2bf(accK[mt][nt][r]);
      }
  __syncthreads();
  for (int c = t; c < 2048; c += 256){
    int row = c >> 4, col8 = (c & 15) * 8;
    *(uint4*)(keys + ((size_t)a * B_N + row0 + row) * H_N + col8) =
        *(const uint4*)&T[row * 136 + col8];
  }
}

// ---------------------------------------------------------------------------
// Attention: block = 8 b-rows, all agents/heads in LDS. `other` may alias
// `keys` (all global reads complete before __syncthreads; rows disjoint
// across blocks).
// ---------------------------------------------------------------------------
__global__ __launch_bounds__(256) void k_attn(
    const u16* __restrict__ sels, const u16* __restrict__ keys,
    const u16* __restrict__ vals, u16* __restrict__ other)
{
  int b0 = blockIdx.x * 8;
  int t = threadIdx.x;
  __shared__ __align__(16) u16 sS[8192], sK[8192], sV[8192];
  u32* dS = (u32*)sS; u32* dK = (u32*)sK; u32* dV = (u32*)sV;
  #pragma unroll
  for (int a = 0; a < 8; ++a){
    size_t go = ((size_t)a * B_N + b0) * KD_N;
    const u32* gs = (const u32*)(sels + go);
    const u32* gk = (const u32*)(keys + go);
    const u32* gv = (const u32*)(vals + go);
    dS[a * 512 + t] = gs[t]; dS[a * 512 + 256 + t] = gs[256 + t];
    dK[a * 512 + t] = gk[t]; dK[a * 512 + 256 + t] = gk[256 + t];
    dV[a * 512 + t] = gv[t]; dV[a * 512 + 256 + t] = gv[256 + t];
  }
  __syncthreads();
  int i = t & 7, p = t >> 3;
  int k = p & 3, bl = p >> 2;
  int base_i = (i * 8 + bl) * 128 + k * 32;
  float si[32];
  {
    const u32* S32 = (const u32*)&sS[base_i];
    #pragma unroll
    for (int d2 = 0; d2 < 16; ++d2){
      u32 u = S32[d2];
      si[2 * d2] = bf_lo(u); si[2 * d2 + 1] = bf_hi(u);
    }
  }
  float lg[8];
  #pragma unroll
  for (int j = 0; j < 8; ++j){
    const u32* K32 = (const u32*)&sK[(j * 8 + bl) * 128 + k * 32];
    float acc = 0.f;
    #pragma unroll
    for (int d2 = 0; d2 < 16; ++d2){
      u32 u = K32[d2];
      acc = fmaf(si[2 * d2], bf_lo(u), acc);
      acc = fmaf(si[2 * d2 + 1], bf_hi(u), acc);
    }
    lg[j] = acc * 0.17677669529663689f;
  }
  float mx = -3.0e38f;
  #pragma unroll
  for (int j = 0; j < 8; ++j) if (j != i) mx = fmaxf(mx, lg[j]);
  float pe[8], se = 0.f;
  #pragma unroll
  for (int j = 0; j < 8; ++j){
    pe[j] = (j == i) ? 0.f : __expf(lg[j] - mx);
    se += pe[j];
  }
  float inv = 1.f / se;
  #pragma unroll
  for (int j = 0; j < 8; ++j) pe[j] *= inv;
  __align__(16) u16 ob[32];
  #pragma unroll
  for (int d2 = 0; d2 < 16; ++d2){
    float acc0 = 0.f, acc1 = 0.f;
    #pragma unroll
    for (int j = 0; j < 8; ++j){
      u32 u = *(const u32*)&sV[(j * 8 + bl) * 128 + k * 32 + 2 * d2];
      acc0 = fmaf(pe[j], bf_lo(u), acc0);
      acc1 = fmaf(pe[j], bf_hi(u), acc1);
    }
    ob[2 * d2] = f2bf(acc0); ob[2 * d2 + 1] = f2bf(acc1);
  }
  uint4* dst = (uint4*)(other + ((size_t)i * B_N + (b0 + bl)) * KD_N + k * 32);
  const uint4* s4 = (const uint4*)ob;
  #pragma unroll
  for (int c = 0; c < 4; ++c) dst[c] = s4[c];
}

// ---------------------------------------------------------------------------
// Critic: h = lrelu([sa_enc|other]@c1_w + c1_b); q = h.c2_w + c2_b.
// 1-term c1, NO LDS, NO barriers: A-frags direct from sa_enc/other
// (64B-line coalesced), B-frags direct from L2-resident c1H.
// ---------------------------------------------------------------------------
__global__ __launch_bounds__(256, 3) void k_critic(
    const u16* __restrict__ sa_enc, const u16* __restrict__ other,
    const u16* __restrict__ c1H, const float* __restrict__ c1_b,
    const float* __restrict__ c2w, const float* __restrict__ c2b,
    float* __restrict__ qout)
{
  int a = blockIdx.y; int row0 = blockIdx.x * 128; int t = threadIdx.x;
  int lane = t & 63, wave = t >> 6, l16 = lane & 15, quad = lane >> 4;
  floatx4 acc[2][8];
  #pragma unroll
  for (int mt = 0; mt < 2; ++mt)
    #pragma unroll
    for (int nt = 0; nt < 8; ++nt) acc[mt][nt] = (floatx4){0.f,0.f,0.f,0.f};
  const u16* wb = c1H + (size_t)a * H_N * CIN_N;
  size_t rbase[2];
  #pragma unroll
  for (int mt = 0; mt < 2; ++mt)
    rbase[mt] = ((size_t)a * B_N + row0 + wave * 32 + mt * 16 + l16) * H_N;

  #pragma unroll
  for (int kt = 0; kt < 8; ++kt){
    int k0 = kt * 32;
    int fo = (k0 & 127) + quad * 8;
    const u16* src = (kt < 4) ? sa_enc : other;
    short8 ah[2], bh[8];
    #pragma unroll
    for (int mt = 0; mt < 2; ++mt)
      ah[mt] = *(const short8*)(src + rbase[mt] + fo);
    #pragma unroll
    for (int nt = 0; nt < 8; ++nt)
      bh[nt] = *(const short8*)(wb + (size_t)(nt * 16 + l16) * CIN_N + k0 + quad * 8);
    #pragma unroll
    for (int mt = 0; mt < 2; ++mt)
      #pragma unroll
      for (int nt = 0; nt < 8; ++nt)
        acc[mt][nt] = __builtin_amdgcn_mfma_f32_16x16x32_bf16(ah[mt], bh[nt], acc[mt][nt], 0,0,0);
  }

  float c2r[8], bv[8];
  #pragma unroll
  for (int nt = 0; nt < 8; ++nt){
    c2r[nt] = c2w[a * H_N + nt * 16 + l16];
    bv[nt]  = c1_b[a * H_N + nt * 16 + l16];
  }
  #pragma unroll
  for (int mt = 0; mt < 2; ++mt){
    #pragma unroll
    for (int r = 0; r < 4; ++r){
      float s = 0.f;
      #pragma unroll
      for (int nt = 0; nt < 8; ++nt){
        float h = lrelu(acc[mt][nt][r] + bv[nt]);
        s = fmaf(h, c2r[nt], s);
      }
      s += __shfl_xor(s, 1);
      s += __shfl_xor(s, 2);
      s += __shfl_xor(s, 4);
      s += __shfl_xor(s, 8);
      if (l16 == 0){
        int row = row0 + wave * 32 + mt * 16 + quad * 4 + r;
        qout[(size_t)a * B_N + row] = s + c2b[a];
      }
    }
  }
}

// ---------------------------------------------------------------------------
extern "C" void kernel_launch(void* const* d_in, const int* in_sizes, int n_in,
                              void* d_out, int out_size, void* d_ws, size_t ws_size,
                              hipStream_t stream)
{
  const float* states  = (const float*)d_in[0];
  const float* actions = (const float*)d_in[1];
  const float* enc_w   = (const float*)d_in[2];
  const float* enc_b   = (const float*)d_in[3];
  const float* aenc_w  = (const float*)d_in[4];
  const float* aenc_b  = (const float*)d_in[5];
  const float* key_w   = (const float*)d_in[6];
  const float* sel_w   = (const float*)d_in[7];
  const float* val_w   = (const float*)d_in[8];
  const float* val_b   = (const float*)d_in[9];
  const float* c1_w    = (const float*)d_in[10];
  const float* c1_b    = (const float*)d_in[11];
  const float* c2_w    = (const float*)d_in[12];
  const float* c2_b    = (const float*)d_in[13];
  float* q = (float*)d_out;

  char* ws = (char*)d_ws;
  // Pack region [0, 1,015,808) overlaps stats partials [0, 1,310,720):
  // stats/finalize consume `part` before k_pack overwrites (sequential stream).
  u16* encH  = (u16*)(ws + 0);          // 393216 B
  u16* encL  = (u16*)(ws + 393216);     // 393216 B
  u16* aencH = (u16*)(ws + 786432);     //  65536 B
  u16* aencL = (u16*)(ws + 851968);     //  65536 B
  u16* keyH  = (u16*)(ws + 917504);     //  32768 B
  u16* selH  = (u16*)(ws + 950272);     //  32768 B
  u16* valH  = (u16*)(ws + 983040);     //  32768 B -> ends 1,015,808
  float* part    = (float*)ws;          // 1,310,720 B (dead after finalize)
  float* meanArr = (float*)(ws + 1310720);
  float* istdArr = (float*)(ws + 1315840);
  u16* c1H = (u16*)(ws + 1320960);      // 524288 B -> ends 1,845,248
  const size_t ibase = 4194304;
  const size_t BUF = (size_t)A_N * B_N * 128 * 2;   // 64 MB
  u16* sa_enc = (u16*)(ws + ibase);
  u16* sels   = (u16*)(ws + ibase + BUF);
  u16* keys   = (u16*)(ws + ibase + 2 * BUF);       // keys, later `other`
  u16* vals   = (u16*)(ws + ibase + 3 * BUF);

  k_stats<<<dim3(CHUNKS, A_N), 256, 0, stream>>>(states, actions, part);
  k_finalize<<<(A_N * SAF + 255) / 256, 256, 0, stream>>>(part, meanArr, istdArr);
  k_pack<<<(PACK_TOTAL + 255) / 256, 256, 0, stream>>>(
      enc_w, aenc_w, key_w, sel_w, val_w, c1_w,
      encH, encL, aencH, aencL, keyH, selH, valH, c1H);

  dim3 g(B_N / 128, A_N);
  k_enc_sel<<<g, 256, 0, stream>>>(states, actions, meanArr, istdArr,
                                   encH, encL, enc_b, selH, sa_enc, sels);
  k_aenc_kv<<<g, 256, 0, stream>>>(actions, meanArr, istdArr,
                                   aencH, aencL, aenc_b, keyH, valH, val_b,
                                   keys, vals);
  k_attn<<<B_N / 8, 256, 0, stream>>>(sels, keys, vals, keys);  // other -> keys
  k_critic<<<g, 256, 0, stream>>>(sa_enc, keys, c1H, c1_b, c2_w, c2_b, q);
}